// Round 9
// baseline (284.890 us; speedup 1.0000x reference)
//
#include <hip/hip_runtime.h>
#include <hip/hip_bf16.h>

#define BATCH 32
#define HW1 224

typedef __attribute__((ext_vector_type(8))) short short8;
typedef __attribute__((ext_vector_type(4))) float floatx4;

static __device__ __forceinline__ unsigned short f2bf(float f) {
    unsigned int u = __float_as_uint(f);
    unsigned int r = (u + 0x7fffu + ((u >> 16) & 1u)) >> 16;   // RNE
    return (unsigned short)r;
}

// async 16B global -> LDS. Only used in the proven single-call-site,
// single-array staging pattern (conv2/conv3).
typedef __attribute__((address_space(1))) const unsigned int guint;
typedef __attribute__((address_space(3))) unsigned int suint;
static __device__ __forceinline__ void gload_lds16(const void* g, void* l) {
    __builtin_amdgcn_global_load_lds((guint*)g, (suint*)l, 16, 0, 0);
}

#define MFMA(A, B, C) __builtin_amdgcn_mfma_f32_16x16x32_bf16((A), (B), (C), 0, 0, 0)

// ---------------------------------------------------------------------------
// Kernel A: blocks [0,216): MLP -> conv1 dyn weights in packed swA/swB bf16
// layout (swpre). Block 216: BN const folding + feat zero + fc-counter zero.
// (conv2/conv3 weight repack moved into conv1's first 360 blocks.)
// ---------------------------------------------------------------------------
__global__ __launch_bounds__(256) void gen_dynw(
    const float* __restrict__ w1, const float* __restrict__ b1,
    const float* __restrict__ w2, const float* __restrict__ b2,
    const float* __restrict__ w3, const float* __restrict__ b3,
    const float* __restrict__ wb, const float* __restrict__ bb,
    const float* __restrict__ conv2_b, const float* __restrict__ conv3_b,
    const float* __restrict__ bn1_g, const float* __restrict__ bn1_b,
    const float* __restrict__ bn1_m, const float* __restrict__ bn1_v,
    const float* __restrict__ bn2_g, const float* __restrict__ bn2_b,
    const float* __restrict__ bn2_m, const float* __restrict__ bn2_v,
    const float* __restrict__ bn3_g, const float* __restrict__ bn3_b,
    const float* __restrict__ bn3_m, const float* __restrict__ bn3_v,
    unsigned short* __restrict__ swpre,
    float* __restrict__ bn1_s, float* __restrict__ bn1_t,
    float* __restrict__ bn2_s, float* __restrict__ bn2_t,
    float* __restrict__ bn3_s, float* __restrict__ bn3_t,
    float* __restrict__ feat, int* __restrict__ cnt)
{
    __shared__ float h1s[128];
    __shared__ float h2s[256];
    const int blk = blockIdx.x;
    const int t = threadIdx.x;
    if (blk < 216) {
        if (t < 128) {
            float s = b1[t] + w1[t*3+0] + w1[t*3+1] + w1[t*3+2];
            h1s[t] = fmaxf(s, 0.f);
        }
        __syncthreads();
        {
            float s0 = b2[t], s1 = 0.f, s2 = 0.f, s3 = 0.f;
            const float* wr = w2 + (size_t)t*128;
#pragma unroll 4
            for (int k = 0; k < 128; k += 4) {
                float4 wv = *(const float4*)(wr + k);
                s0 = fmaf(wv.x, h1s[k  ], s0);
                s1 = fmaf(wv.y, h1s[k+1], s1);
                s2 = fmaf(wv.z, h1s[k+2], s2);
                s3 = fmaf(wv.w, h1s[k+3], s3);
            }
            h2s[t] = fmaxf((s0 + s1) + (s2 + s3), 0.f);
        }
        __syncthreads();
        const int wave = t >> 6, lane = t & 63;
        const int row = blk*4 + wave;          // row = oc*27 + tap
        float4 wv = *(const float4*)(w3 + (size_t)row*256 + lane*4);
        float4 hv = *(const float4*)&h2s[lane*4];
        float s = wv.x*hv.x + wv.y*hv.y + wv.z*hv.z + wv.w*hv.w;
#pragma unroll
        for (int m = 1; m < 64; m <<= 1) s += __shfl_xor(s, m);
        if (lane == 0) {
            int oc = row / 27, tap = row - oc*27;   // tap = ic*9 + ky*3 + kx
            int ic = tap / 9, kk = tap - ic*9;
            int ky = kk / 3, kx = kk - ky*3;
            unsigned short v = f2bf(s + b3[row]);
            int pos;
            if (kk == 8)      pos = 1024 + oc*32 + ic;
            else if (kx < 2)  pos = oc*32 + ky*8 + kx*4 + ic;
            else              pos = oc*32 + 24 + ky*4 + ic;
            swpre[pos] = v;
        }
    } else {
        if (t < 32) {
            float dynb = bb[t] + wb[t*3+0] + wb[t*3+1] + wb[t*3+2];
            float s = bn1_g[t] / sqrtf(bn1_v[t] + 1e-5f);
            bn1_s[t] = s;
            bn1_t[t] = (dynb - bn1_m[t]) * s + bn1_b[t];
        }
        if (t < 64) {
            float s = bn2_g[t] / sqrtf(bn2_v[t] + 1e-5f);
            bn2_s[t] = s;
            bn2_t[t] = (conv2_b[t] - bn2_m[t]) * s + bn2_b[t];
        }
        if (t < 128) {
            float s = bn3_g[t] / sqrtf(bn3_v[t] + 1e-5f);
            bn3_s[t] = s;
            bn3_t[t] = (conv3_b[t] - bn3_m[t]) * s + bn3_b[t];
        }
        for (int i = t; i < BATCH*128; i += 256) feat[i] = 0.f;
        if (t == 0) *cnt = 0;
    }
}

// ---------------------------------------------------------------------------
// Kernel B: conv1 (3->32, 224x224, pad1) + bn + relu + 2x2 maxpool, via MFMA.
// First 360 blocks additionally repack conv2/conv3 weights (1 ld + 1 st per
// thread, hidden under staging latency; consumed only by later kernels).
// ---------------------------------------------------------------------------
__global__ __launch_bounds__(256) void conv1_pool(
    const float* __restrict__ x,
    const unsigned short* __restrict__ swpre,
    const float* __restrict__ conv2_w, const float* __restrict__ conv3_w,
    unsigned short* __restrict__ wrep2, unsigned short* __restrict__ wrep3,
    const float* __restrict__ bn_s, const float* __restrict__ bn_t,
    unsigned short* __restrict__ act1)
{
    __shared__ __align__(16) unsigned short sp[18*20*4];   // 2880 B
    __shared__ __align__(16) unsigned short swAB[2048];    // swA | swB

    const int tid = threadIdx.x;
    const int bx = blockIdx.x, by = blockIdx.y, b = blockIdx.z;

    // ---- distributed conv2/conv3 weight repack (blocks 0..359) ----
    {
        int flat = (b*14 + by)*14 + bx;
        if (flat < 360) {
            int i = flat*256 + tid;            // < 92160
            const int N2 = 9*64*32;            // 18432
            if (i < N2) {
                int tp = i / (64*32); int rem = i - tp*(64*32);
                int oc = rem >> 5, ic = rem & 31;
                wrep2[i] = f2bf(conv2_w[(oc*32 + ic)*9 + tp]);
            } else {
                int j = i - N2;                // j < 9*128*64
                int tp = j / (128*64); int rem = j - tp*(128*64);
                int oc = rem >> 6, ic = rem & 63;
                wrep3[j] = f2bf(conv3_w[(oc*64 + ic)*9 + tp]);
            }
        }
    }

    const int gy0 = by*16 - 1;
    const int gxs0 = bx*16 - 2;      // sp col 0 (even -> aligned float2)
    const float* xb = x + (size_t)b * 3 * HW1 * HW1;

    // ---- weights: one masked vector copy ----
    {
        uint4 w = *(const uint4*)(swpre + tid*8);
        if (tid < 128) {                       // swA: slot%4==3 dead
            w.y &= 0xFFFFu; w.w &= 0xFFFFu;    // ushorts 3 and 7
        } else if (((tid*8) & 31) != 0) {      // swB: off>=8 all dead
            w.x = 0u; w.y = 0u; w.z = 0u; w.w = 0u;
        } else {                               // swB off 0..7: keep 0..2
            w.y &= 0xFFFFu; w.z = 0u; w.w = 0u;
        }
        *(uint4*)&swAB[tid*8] = w;
    }

    // ---- x: 180 pixel-pairs, aligned float2 per channel ----
    float2 c0 = {0.f, 0.f}, c1 = {0.f, 0.f}, c2 = {0.f, 0.f};
    if (tid < 180) {
        int row = tid / 10, p = tid - row*10;
        int gy = gy0 + row, gx = gxs0 + p*2;
        if (((unsigned)gy < HW1) && ((unsigned)gx <= 222u)) {
            const float* pp = xb + gy*HW1 + gx;
            c0 = *(const float2*)(pp);
            c1 = *(const float2*)(pp + HW1*HW1);
            c2 = *(const float2*)(pp + 2*HW1*HW1);
        }
        uint4 v;
        v.x = (unsigned int)f2bf(c0.x) | ((unsigned int)f2bf(c1.x) << 16);
        v.y = (unsigned int)f2bf(c2.x);
        v.z = (unsigned int)f2bf(c0.y) | ((unsigned int)f2bf(c1.y) << 16);
        v.w = (unsigned int)f2bf(c2.y);
        *(uint4*)&sp[tid*8] = v;
    }
    __syncthreads();

    const int lane = tid & 63, wave = tid >> 6;
    const int n = lane & 15, quad = lane >> 4;

    short8 afrA[2], afrB[2];
#pragma unroll
    for (int h = 0; h < 2; ++h) {
        afrA[h] = *(const short8*)&swAB[((h*16 + n)*32) + quad*8];
        afrB[h] = *(const short8*)&swAB[1024 + ((h*16 + n)*32) + quad*8];
    }
    float4 sv[2], tv[2];
#pragma unroll
    for (int h = 0; h < 2; ++h) {
        sv[h] = *(const float4*)(bn_s + h*16 + quad*4);
        tv[h] = *(const float4*)(bn_t + h*16 + quad*4);
    }

    union U { short8 s8; uint2 u2[2]; };

    const int y0w = wave*4;
    float ev[2][4];

#pragma unroll
    for (int yi = 0; yi < 4; ++yi) {
        const int y = y0w + yi;
        int r0 = (quad < 3) ? (y + quad) : y;
        int c0i = (quad < 3) ? n : (n + 2);
        int r1 = (quad < 3) ? (y + quad) : (y + 1);
        int c1i = (quad < 3) ? (n + 1) : (n + 2);
        U bf1;
        bf1.u2[0] = *(const uint2*)&sp[(r0*20 + c0i + 1)*4];
        bf1.u2[1] = *(const uint2*)&sp[(r1*20 + c1i + 1)*4];
        U bf2;
        bf2.u2[0] = *(const uint2*)&sp[((y+2)*20 + (n+3))*4];
        bf2.u2[1] = bf2.u2[0];

        float vr[2][4];
#pragma unroll
        for (int h = 0; h < 2; ++h) {
            floatx4 acc = {0.f, 0.f, 0.f, 0.f};
            acc = MFMA(afrA[h], bf1.s8, acc);
            acc = MFMA(afrB[h], bf2.s8, acc);
            float sj[4] = {sv[h].x, sv[h].y, sv[h].z, sv[h].w};
            float tj[4] = {tv[h].x, tv[h].y, tv[h].z, tv[h].w};
#pragma unroll
            for (int j = 0; j < 4; ++j)
                vr[h][j] = fmaxf(fmaf(acc[j], sj[j], tj[j]), 0.f);
        }

        if ((yi & 1) == 0) {
#pragma unroll
            for (int h = 0; h < 2; ++h)
#pragma unroll
                for (int j = 0; j < 4; ++j) ev[h][j] = vr[h][j];
        } else {
            int py = by*8 + ((y0w + yi) >> 1);
            int px = bx*8 + (n >> 1);
            unsigned short* dstp =
                act1 + ((size_t)((b*112 + py)*112 + px))*32 + quad*4;
#pragma unroll
            for (int h = 0; h < 2; ++h) {
                unsigned int pk[2];
#pragma unroll
                for (int j = 0; j < 4; ++j) {
                    float m = fmaxf(vr[h][j], ev[h][j]);
                    m = fmaxf(m, __shfl_xor(m, 1));
                    unsigned short us = f2bf(m);
                    if (j & 1) pk[j >> 1] |= ((unsigned int)us) << 16;
                    else       pk[j >> 1]  = us;
                }
                if (!(n & 1)) *(uint2*)(dstp + h*16) = *(uint2*)pk;
            }
        }
    }
}

// ---------------------------------------------------------------------------
// Kernel C: conv2 (32->64, 112x112) bf16 MFMA + bn + relu + 2x2 maxpool.
// R1 structure verbatim (rolling-row-window).
// ---------------------------------------------------------------------------
__global__ __launch_bounds__(256) void conv2_mfma(
    const unsigned short* __restrict__ act1,
    const unsigned short* __restrict__ wrep,
    const float* __restrict__ bn_s, const float* __restrict__ bn_t,
    unsigned short* __restrict__ act2)
{
    constexpr int IC = 32, OC = 64, H = 112;
    __shared__ __align__(16) short lds[4*18*18*8];   // [chunk][y][x][8ic]

    const int tid = threadIdx.x;
    const int b = blockIdx.z;
    const int cx0 = blockIdx.x*16, cy0 = blockIdx.y*16;
    const unsigned short* ab = act1 + (size_t)b*H*H*IC;

    unsigned bad = 0;
    {
        int k = 0;
        for (int s = tid; s < 4*324; s += 256, ++k) {
            int ck = s / 324; int rem = s - ck*324;
            int y = rem / 18, xx = rem - y*18;
            int gy = cy0 - 1 + y, gx = cx0 - 1 + xx;
            if (!(((unsigned)gy < H) && ((unsigned)gx < H))) {
                bad |= 1u << k; gy = 0; gx = 0;
            }
            gload_lds16(ab + (size_t)(gy*H + gx)*IC + ck*8, &lds[s*8]);
        }
        if (bad) {
            asm volatile("s_waitcnt vmcnt(0)" ::: "memory");
            k = 0;
            for (int s = tid; s < 4*324; s += 256, ++k)
                if (bad & (1u << k)) {
                    uint4 z = {0u,0u,0u,0u};
                    *(uint4*)&lds[s*8] = z;
                }
        }
    }

    const int lane = tid & 63, wave = tid >> 6;
    const int n = lane & 15, quad = lane >> 4;
    const int oc0w = wave * 16;

    short8 afr[9];
#pragma unroll
    for (int t = 0; t < 9; ++t)
        afr[t] = *(const short8*)(wrep + (size_t)(t*OC + oc0w + n)*IC + quad*8);

    float4 sv = *(const float4*)(bn_s + oc0w + quad*4);
    float4 tv = *(const float4*)(bn_t + oc0w + quad*4);
    float sj[4] = {sv.x, sv.y, sv.z, sv.w};
    float tj[4] = {tv.x, tv.y, tv.z, tv.w};

    __syncthreads();

    floatx4 acc[3];
    float ev[4];

#pragma unroll
    for (int r = 0; r < 18; ++r) {
        const short* rp = &lds[((quad*18 + r)*18 + n)*8];
        short8 w0 = *(const short8*)(rp);
        short8 w1 = *(const short8*)(rp + 8);
        short8 w2 = *(const short8*)(rp + 16);

        if (r < 16) {
            floatx4 a = {0.f,0.f,0.f,0.f};
            a = MFMA(afr[0], w0, a);
            a = MFMA(afr[1], w1, a);
            a = MFMA(afr[2], w2, a);
            acc[r % 3] = a;
        }
        if (r >= 1 && r <= 16) {
            int y = r - 1;
            floatx4 a = acc[y % 3];
            a = MFMA(afr[3], w0, a);
            a = MFMA(afr[4], w1, a);
            a = MFMA(afr[5], w2, a);
            acc[y % 3] = a;
        }
        if (r >= 2) {
            int y = r - 2;
            floatx4 a = acc[y % 3];
            a = MFMA(afr[6], w0, a);
            a = MFMA(afr[7], w1, a);
            a = MFMA(afr[8], w2, a);

            float v[4];
#pragma unroll
            for (int j = 0; j < 4; ++j)
                v[j] = fmaxf(fmaf(a[j], sj[j], tj[j]), 0.f);

            if ((y & 1) == 0) {
#pragma unroll
                for (int j = 0; j < 4; ++j) ev[j] = v[j];
            } else {
                unsigned int pk[2];
#pragma unroll
                for (int j = 0; j < 4; ++j) {
                    float m = fmaxf(v[j], ev[j]);
                    m = fmaxf(m, __shfl_xor(m, 1));
                    unsigned short us = f2bf(m);
                    if (j & 1) pk[j >> 1] |= ((unsigned int)us) << 16;
                    else       pk[j >> 1]  = us;
                }
                if (!(n & 1)) {
                    int py = (cy0 >> 1) + (y >> 1), px = (cx0 >> 1) + (n >> 1);
                    unsigned short* dstp =
                        act2 + ((size_t)((b*56 + py)*56 + px))*OC + oc0w + quad*4;
                    *(uint2*)dstp = *(uint2*)pk;
                }
            }
        }
    }
}

// ---------------------------------------------------------------------------
// Kernel D: conv3 (64->128, 56x56) bf16 MFMA + bn + relu + spatial mean sum
// into feat, then LAST arriving block (device-scope counter) computes the
// whole FC head from coherent feat reads. Sole writer of d_out, written once
// at the very end of the launch.
// ---------------------------------------------------------------------------
__global__ __launch_bounds__(256) void conv3_mfma_fc(
    const unsigned short* __restrict__ act2,
    const unsigned short* __restrict__ wrep,
    const float* __restrict__ bn_s, const float* __restrict__ bn_t,
    float* __restrict__ feat, int* __restrict__ cnt,
    const float* __restrict__ fc_w, const float* __restrict__ fc_b,
    float* __restrict__ out)
{
    constexpr int IC = 64, OC = 128, H = 56;
    __shared__ __align__(16) short lds[8*16*18*8];   // 36.9 KB
    __shared__ int lastflag;

    const int tid = threadIdx.x;
    const int b = blockIdx.z >> 1, half = blockIdx.z & 1;
    const int cx0 = blockIdx.x*16, cy0 = blockIdx.y*14;
    const unsigned short* ab = act2 + (size_t)b*H*H*IC;

    unsigned bad = 0;
    {
        int k = 0;
        for (int s = tid; s < 8*16*18; s += 256, ++k) {   // 2304 = 9 full rounds
            int ck = s / (16*18); int rem = s - ck*(16*18);
            int y = rem / 18, xx = rem - y*18;
            int gy = cy0 - 1 + y, gx = cx0 - 1 + xx;
            if (!(((unsigned)gy < H) && ((unsigned)gx < H))) {
                bad |= 1u << k; gy = 0; gx = 0;
            }
            gload_lds16(ab + (size_t)(gy*H + gx)*IC + ck*8, &lds[s*8]);
        }
        if (bad) {
            asm volatile("s_waitcnt vmcnt(0)" ::: "memory");
            k = 0;
            for (int s = tid; s < 8*16*18; s += 256, ++k)
                if (bad & (1u << k)) {
                    uint4 z = {0u,0u,0u,0u};
                    *(uint4*)&lds[s*8] = z;
                }
        }
    }

    const int lane = tid & 63, wave = tid >> 6;
    const int n = lane & 15, quad = lane >> 4;
    const int oc0w = half*64 + wave*16;

    short8 afr[18];   // [tap][kc]
#pragma unroll
    for (int t = 0; t < 9; ++t)
#pragma unroll
        for (int kc = 0; kc < 2; ++kc)
            afr[t*2 + kc] = *(const short8*)(wrep + (size_t)(t*OC + oc0w + n)*IC + kc*32 + quad*8);

    float4 sv = *(const float4*)(bn_s + oc0w + quad*4);
    float4 tv = *(const float4*)(bn_t + oc0w + quad*4);
    float sj[4] = {sv.x, sv.y, sv.z, sv.w};
    float tj[4] = {tv.x, tv.y, tv.z, tv.w};

    __syncthreads();

    float sum[4] = {0.f, 0.f, 0.f, 0.f};
    const bool vx = (cx0 + n) < H;
    floatx4 acc[3];

#pragma unroll
    for (int r = 0; r < 16; ++r) {
        const short* p0 = &lds[((quad*16     + r)*18 + n)*8];
        const short* p1 = &lds[(((4+quad)*16 + r)*18 + n)*8];
        short8 a0 = *(const short8*)(p0);
        short8 a1 = *(const short8*)(p0 + 8);
        short8 a2 = *(const short8*)(p0 + 16);
        short8 b0 = *(const short8*)(p1);
        short8 b1 = *(const short8*)(p1 + 8);
        short8 b2 = *(const short8*)(p1 + 16);

        if (r < 14) {                    // ky=0 for out y=r (init)
            floatx4 a = {0.f,0.f,0.f,0.f};
            a = MFMA(afr[0], a0, a);
            a = MFMA(afr[1], b0, a);
            a = MFMA(afr[2], a1, a);
            a = MFMA(afr[3], b1, a);
            a = MFMA(afr[4], a2, a);
            a = MFMA(afr[5], b2, a);
            acc[r % 3] = a;
        }
        if (r >= 1 && r <= 14) {         // ky=1 for out y=r-1
            int y = r - 1;
            floatx4 a = acc[y % 3];
            a = MFMA(afr[6],  a0, a);
            a = MFMA(afr[7],  b0, a);
            a = MFMA(afr[8],  a1, a);
            a = MFMA(afr[9],  b1, a);
            a = MFMA(afr[10], a2, a);
            a = MFMA(afr[11], b2, a);
            acc[y % 3] = a;
        }
        if (r >= 2) {                    // ky=2 for out y=r-2, finalize
            int y = r - 2;
            floatx4 a = acc[y % 3];
            a = MFMA(afr[12], a0, a);
            a = MFMA(afr[13], b0, a);
            a = MFMA(afr[14], a1, a);
            a = MFMA(afr[15], b1, a);
            a = MFMA(afr[16], a2, a);
            a = MFMA(afr[17], b2, a);
            if (vx) {
#pragma unroll
                for (int j = 0; j < 4; ++j)
                    sum[j] += fmaxf(fmaf(a[j], sj[j], tj[j]), 0.f);
            }
        }
    }
#pragma unroll
    for (int j = 0; j < 4; ++j) {
        sum[j] += __shfl_xor(sum[j], 1);
        sum[j] += __shfl_xor(sum[j], 2);
        sum[j] += __shfl_xor(sum[j], 4);
        sum[j] += __shfl_xor(sum[j], 8);
    }
    if (n == 0) {
#pragma unroll
        for (int j = 0; j < 4; ++j)
            atomicAdd(&feat[b*128 + oc0w + quad*4 + j], sum[j]);
    }

    // ---- last-block FC ----
    __threadfence();                       // feat adds globally visible
    __syncthreads();
    if (tid == 0) lastflag = (atomicAdd(cnt, 1) == 4*4*BATCH*2 - 1) ? 1 : 0;
    __syncthreads();
    if (lastflag) {
        float* lfeat = (float*)lds;        // 4096 floats = 16 KB
        for (int i = tid; i < BATCH*128; i += 256)
            lfeat[i] = atomicAdd(&feat[i], 0.f);   // coherent read
        __syncthreads();
        for (int g = tid; g < BATCH*100; g += 256) {
            int bb2 = g / 100, nn = g - bb2*100;
            const float* fw = fc_w + (size_t)nn*128;
            const float* fl = lfeat + bb2*128;
            float s = 0.f;
#pragma unroll 4
            for (int k = 0; k < 128; k += 4) {
                float4 wv = *(const float4*)(fw + k);
                s = fmaf(fl[k  ], wv.x, s);
                s = fmaf(fl[k+1], wv.y, s);
                s = fmaf(fl[k+2], wv.z, s);
                s = fmaf(fl[k+3], wv.w, s);
            }
            out[g] = s * (1.f/3136.f) + fc_b[nn];
        }
    }
}

extern "C" void kernel_launch(void* const* d_in, const int* in_sizes, int n_in,
                              void* d_out, int out_size, void* d_ws, size_t ws_size,
                              hipStream_t stream)
{
    const float* x       = (const float*)d_in[0];
    const float* w1      = (const float*)d_in[1];
    const float* b1      = (const float*)d_in[2];
    const float* w2      = (const float*)d_in[3];
    const float* b2      = (const float*)d_in[4];
    const float* w3      = (const float*)d_in[5];
    const float* b3      = (const float*)d_in[6];
    const float* wb      = (const float*)d_in[7];
    const float* bb      = (const float*)d_in[8];
    const float* conv2_w = (const float*)d_in[9];
    const float* conv2_b = (const float*)d_in[10];
    const float* conv3_w = (const float*)d_in[11];
    const float* conv3_b = (const float*)d_in[12];
    const float* bn1_g = (const float*)d_in[13];
    const float* bn1_b = (const float*)d_in[14];
    const float* bn1_m = (const float*)d_in[15];
    const float* bn1_v = (const float*)d_in[16];
    const float* bn2_g = (const float*)d_in[17];
    const float* bn2_b = (const float*)d_in[18];
    const float* bn2_m = (const float*)d_in[19];
    const float* bn2_v = (const float*)d_in[20];
    const float* bn3_g = (const float*)d_in[21];
    const float* bn3_b = (const float*)d_in[22];
    const float* bn3_m = (const float*)d_in[23];
    const float* bn3_v = (const float*)d_in[24];
    const float* fc_w  = (const float*)d_in[25];
    const float* fc_b  = (const float*)d_in[26];
    float* out = (float*)d_out;

    char* wsb = (char*)d_ws;
    float* ws    = (float*)d_ws;
    float* bn1_s = ws + 864;
    float* bn1_t = ws + 896;
    float* bn2_s = ws + 928;
    float* bn2_t = ws + 992;
    float* bn3_s = ws + 1056;
    float* bn3_t = ws + 1184;
    float* feat  = ws + 1312;                                  // bytes [5248,21632)
    int*   cnt   = (int*)(wsb + 22016);                        // fc counter
    unsigned short* swpre = (unsigned short*)(wsb + 24576);    // 2048 ush
    unsigned short* wrep2 = (unsigned short*)(wsb + 32768);    // 18432 ush
    unsigned short* wrep3 = (unsigned short*)(wsb + 69632);    // 73728 ush
    unsigned short* act1  = (unsigned short*)(wsb + 262144);   // 25.7MB
    unsigned short* act2  = (unsigned short*)(wsb + 262144 + 25690112); // 12.8MB

    gen_dynw<<<217, 256, 0, stream>>>(
        w1, b1, w2, b2, w3, b3,
        wb, bb, conv2_b, conv3_b,
        bn1_g, bn1_b, bn1_m, bn1_v, bn2_g, bn2_b, bn2_m, bn2_v,
        bn3_g, bn3_b, bn3_m, bn3_v,
        swpre,
        bn1_s, bn1_t, bn2_s, bn2_t, bn3_s, bn3_t, feat, cnt);

    conv1_pool<<<dim3(14, 14, BATCH), 256, 0, stream>>>(
        x, swpre, conv2_w, conv3_w, wrep2, wrep3, bn1_s, bn1_t, act1);

    conv2_mfma<<<dim3(7, 7, BATCH), 256, 0, stream>>>(
        act1, wrep2, bn2_s, bn2_t, act2);

    conv3_mfma_fc<<<dim3(4, 4, BATCH*2), 256, 0, stream>>>(
        act2, wrep3, bn3_s, bn3_t, feat, cnt, fc_w, fc_b, out);
}

// Round 10
// 180.162 us; speedup vs baseline: 1.5813x; 1.5813x over previous
//
#include <hip/hip_runtime.h>
#include <hip/hip_bf16.h>

#define BATCH 32
#define HW1 224

typedef __attribute__((ext_vector_type(8))) short short8;
typedef __attribute__((ext_vector_type(4))) float floatx4;

static __device__ __forceinline__ unsigned short f2bf(float f) {
    unsigned int u = __float_as_uint(f);
    unsigned int r = (u + 0x7fffu + ((u >> 16) & 1u)) >> 16;   // RNE
    return (unsigned short)r;
}

// async 16B global -> LDS. Only used in the proven single-call-site,
// single-array staging pattern (conv2/conv3).
typedef __attribute__((address_space(1))) const unsigned int guint;
typedef __attribute__((address_space(3))) unsigned int suint;
static __device__ __forceinline__ void gload_lds16(const void* g, void* l) {
    __builtin_amdgcn_global_load_lds((guint*)g, (suint*)l, 16, 0, 0);
}

#define MFMA(A, B, C) __builtin_amdgcn_mfma_f32_16x16x32_bf16((A), (B), (C), 0, 0, 0)

// ---------------------------------------------------------------------------
// Kernel A: blocks [0,216): MLP -> conv1 dyn weights in packed swA/swB bf16
// layout (swpre). Block 216: BN const folding + feat zero.
// (conv2/conv3 weight repack lives in conv1's first 360 blocks.)
// ---------------------------------------------------------------------------
__global__ __launch_bounds__(256) void gen_dynw(
    const float* __restrict__ w1, const float* __restrict__ b1,
    const float* __restrict__ w2, const float* __restrict__ b2,
    const float* __restrict__ w3, const float* __restrict__ b3,
    const float* __restrict__ wb, const float* __restrict__ bb,
    const float* __restrict__ conv2_b, const float* __restrict__ conv3_b,
    const float* __restrict__ bn1_g, const float* __restrict__ bn1_b,
    const float* __restrict__ bn1_m, const float* __restrict__ bn1_v,
    const float* __restrict__ bn2_g, const float* __restrict__ bn2_b,
    const float* __restrict__ bn2_m, const float* __restrict__ bn2_v,
    const float* __restrict__ bn3_g, const float* __restrict__ bn3_b,
    const float* __restrict__ bn3_m, const float* __restrict__ bn3_v,
    unsigned short* __restrict__ swpre,
    float* __restrict__ bn1_s, float* __restrict__ bn1_t,
    float* __restrict__ bn2_s, float* __restrict__ bn2_t,
    float* __restrict__ bn3_s, float* __restrict__ bn3_t,
    float* __restrict__ feat)
{
    __shared__ float h1s[128];
    __shared__ float h2s[256];
    const int blk = blockIdx.x;
    const int t = threadIdx.x;
    if (blk < 216) {
        if (t < 128) {
            float s = b1[t] + w1[t*3+0] + w1[t*3+1] + w1[t*3+2];
            h1s[t] = fmaxf(s, 0.f);
        }
        __syncthreads();
        {
            float s0 = b2[t], s1 = 0.f, s2 = 0.f, s3 = 0.f;
            const float* wr = w2 + (size_t)t*128;
#pragma unroll 4
            for (int k = 0; k < 128; k += 4) {
                float4 wv = *(const float4*)(wr + k);
                s0 = fmaf(wv.x, h1s[k  ], s0);
                s1 = fmaf(wv.y, h1s[k+1], s1);
                s2 = fmaf(wv.z, h1s[k+2], s2);
                s3 = fmaf(wv.w, h1s[k+3], s3);
            }
            h2s[t] = fmaxf((s0 + s1) + (s2 + s3), 0.f);
        }
        __syncthreads();
        const int wave = t >> 6, lane = t & 63;
        const int row = blk*4 + wave;          // row = oc*27 + tap
        float4 wv = *(const float4*)(w3 + (size_t)row*256 + lane*4);
        float4 hv = *(const float4*)&h2s[lane*4];
        float s = wv.x*hv.x + wv.y*hv.y + wv.z*hv.z + wv.w*hv.w;
#pragma unroll
        for (int m = 1; m < 64; m <<= 1) s += __shfl_xor(s, m);
        if (lane == 0) {
            int oc = row / 27, tap = row - oc*27;   // tap = ic*9 + ky*3 + kx
            int ic = tap / 9, kk = tap - ic*9;
            int ky = kk / 3, kx = kk - ky*3;
            unsigned short v = f2bf(s + b3[row]);
            int pos;
            if (kk == 8)      pos = 1024 + oc*32 + ic;
            else if (kx < 2)  pos = oc*32 + ky*8 + kx*4 + ic;
            else              pos = oc*32 + 24 + ky*4 + ic;
            swpre[pos] = v;
        }
    } else {
        if (t < 32) {
            float dynb = bb[t] + wb[t*3+0] + wb[t*3+1] + wb[t*3+2];
            float s = bn1_g[t] / sqrtf(bn1_v[t] + 1e-5f);
            bn1_s[t] = s;
            bn1_t[t] = (dynb - bn1_m[t]) * s + bn1_b[t];
        }
        if (t < 64) {
            float s = bn2_g[t] / sqrtf(bn2_v[t] + 1e-5f);
            bn2_s[t] = s;
            bn2_t[t] = (conv2_b[t] - bn2_m[t]) * s + bn2_b[t];
        }
        if (t < 128) {
            float s = bn3_g[t] / sqrtf(bn3_v[t] + 1e-5f);
            bn3_s[t] = s;
            bn3_t[t] = (conv3_b[t] - bn3_m[t]) * s + bn3_b[t];
        }
        for (int i = t; i < BATCH*128; i += 256) feat[i] = 0.f;
    }
}

// ---------------------------------------------------------------------------
// Kernel B: conv1 (3->32, 224x224, pad1) + bn + relu + 2x2 maxpool, via MFMA.
// First 360 blocks additionally repack conv2/conv3 weights (1 ld + 1 st per
// thread, hidden under staging; consumed only by later kernels — stream
// order guarantees visibility). Harness-proven green in R9.
// ---------------------------------------------------------------------------
__global__ __launch_bounds__(256) void conv1_pool(
    const float* __restrict__ x,
    const unsigned short* __restrict__ swpre,
    const float* __restrict__ conv2_w, const float* __restrict__ conv3_w,
    unsigned short* __restrict__ wrep2, unsigned short* __restrict__ wrep3,
    const float* __restrict__ bn_s, const float* __restrict__ bn_t,
    unsigned short* __restrict__ act1)
{
    __shared__ __align__(16) unsigned short sp[18*20*4];   // 2880 B
    __shared__ __align__(16) unsigned short swAB[2048];    // swA | swB

    const int tid = threadIdx.x;
    const int bx = blockIdx.x, by = blockIdx.y, b = blockIdx.z;

    // ---- distributed conv2/conv3 weight repack (blocks 0..359) ----
    {
        int flat = (b*14 + by)*14 + bx;
        if (flat < 360) {
            int i = flat*256 + tid;            // < 92160
            const int N2 = 9*64*32;            // 18432
            if (i < N2) {
                int tp = i / (64*32); int rem = i - tp*(64*32);
                int oc = rem >> 5, ic = rem & 31;
                wrep2[i] = f2bf(conv2_w[(oc*32 + ic)*9 + tp]);
            } else {
                int j = i - N2;                // j < 9*128*64
                int tp = j / (128*64); int rem = j - tp*(128*64);
                int oc = rem >> 6, ic = rem & 63;
                wrep3[j] = f2bf(conv3_w[(oc*64 + ic)*9 + tp]);
            }
        }
    }

    const int gy0 = by*16 - 1;
    const int gxs0 = bx*16 - 2;      // sp col 0 (even -> aligned float2)
    const float* xb = x + (size_t)b * 3 * HW1 * HW1;

    // ---- weights: one masked vector copy ----
    {
        uint4 w = *(const uint4*)(swpre + tid*8);
        if (tid < 128) {                       // swA: slot%4==3 dead
            w.y &= 0xFFFFu; w.w &= 0xFFFFu;    // ushorts 3 and 7
        } else if (((tid*8) & 31) != 0) {      // swB: off>=8 all dead
            w.x = 0u; w.y = 0u; w.z = 0u; w.w = 0u;
        } else {                               // swB off 0..7: keep 0..2
            w.y &= 0xFFFFu; w.z = 0u; w.w = 0u;
        }
        *(uint4*)&swAB[tid*8] = w;
    }

    // ---- x: 180 pixel-pairs, aligned float2 per channel ----
    float2 c0 = {0.f, 0.f}, c1 = {0.f, 0.f}, c2 = {0.f, 0.f};
    if (tid < 180) {
        int row = tid / 10, p = tid - row*10;
        int gy = gy0 + row, gx = gxs0 + p*2;
        if (((unsigned)gy < HW1) && ((unsigned)gx <= 222u)) {
            const float* pp = xb + gy*HW1 + gx;
            c0 = *(const float2*)(pp);
            c1 = *(const float2*)(pp + HW1*HW1);
            c2 = *(const float2*)(pp + 2*HW1*HW1);
        }
        uint4 v;
        v.x = (unsigned int)f2bf(c0.x) | ((unsigned int)f2bf(c1.x) << 16);
        v.y = (unsigned int)f2bf(c2.x);
        v.z = (unsigned int)f2bf(c0.y) | ((unsigned int)f2bf(c1.y) << 16);
        v.w = (unsigned int)f2bf(c2.y);
        *(uint4*)&sp[tid*8] = v;
    }
    __syncthreads();

    const int lane = tid & 63, wave = tid >> 6;
    const int n = lane & 15, quad = lane >> 4;

    short8 afrA[2], afrB[2];
#pragma unroll
    for (int h = 0; h < 2; ++h) {
        afrA[h] = *(const short8*)&swAB[((h*16 + n)*32) + quad*8];
        afrB[h] = *(const short8*)&swAB[1024 + ((h*16 + n)*32) + quad*8];
    }
    float4 sv[2], tv[2];
#pragma unroll
    for (int h = 0; h < 2; ++h) {
        sv[h] = *(const float4*)(bn_s + h*16 + quad*4);
        tv[h] = *(const float4*)(bn_t + h*16 + quad*4);
    }

    union U { short8 s8; uint2 u2[2]; };

    const int y0w = wave*4;
    float ev[2][4];

#pragma unroll
    for (int yi = 0; yi < 4; ++yi) {
        const int y = y0w + yi;
        int r0 = (quad < 3) ? (y + quad) : y;
        int c0i = (quad < 3) ? n : (n + 2);
        int r1 = (quad < 3) ? (y + quad) : (y + 1);
        int c1i = (quad < 3) ? (n + 1) : (n + 2);
        U bf1;
        bf1.u2[0] = *(const uint2*)&sp[(r0*20 + c0i + 1)*4];
        bf1.u2[1] = *(const uint2*)&sp[(r1*20 + c1i + 1)*4];
        U bf2;
        bf2.u2[0] = *(const uint2*)&sp[((y+2)*20 + (n+3))*4];
        bf2.u2[1] = bf2.u2[0];

        float vr[2][4];
#pragma unroll
        for (int h = 0; h < 2; ++h) {
            floatx4 acc = {0.f, 0.f, 0.f, 0.f};
            acc = MFMA(afrA[h], bf1.s8, acc);
            acc = MFMA(afrB[h], bf2.s8, acc);
            float sj[4] = {sv[h].x, sv[h].y, sv[h].z, sv[h].w};
            float tj[4] = {tv[h].x, tv[h].y, tv[h].z, tv[h].w};
#pragma unroll
            for (int j = 0; j < 4; ++j)
                vr[h][j] = fmaxf(fmaf(acc[j], sj[j], tj[j]), 0.f);
        }

        if ((yi & 1) == 0) {
#pragma unroll
            for (int h = 0; h < 2; ++h)
#pragma unroll
                for (int j = 0; j < 4; ++j) ev[h][j] = vr[h][j];
        } else {
            int py = by*8 + ((y0w + yi) >> 1);
            int px = bx*8 + (n >> 1);
            unsigned short* dstp =
                act1 + ((size_t)((b*112 + py)*112 + px))*32 + quad*4;
#pragma unroll
            for (int h = 0; h < 2; ++h) {
                unsigned int pk[2];
#pragma unroll
                for (int j = 0; j < 4; ++j) {
                    float m = fmaxf(vr[h][j], ev[h][j]);
                    m = fmaxf(m, __shfl_xor(m, 1));
                    unsigned short us = f2bf(m);
                    if (j & 1) pk[j >> 1] |= ((unsigned int)us) << 16;
                    else       pk[j >> 1]  = us;
                }
                if (!(n & 1)) *(uint2*)(dstp + h*16) = *(uint2*)pk;
            }
        }
    }
}

// ---------------------------------------------------------------------------
// Kernel C: conv2 (32->64, 112x112) bf16 MFMA + bn + relu + 2x2 maxpool.
// R1 structure verbatim (rolling-row-window).
// ---------------------------------------------------------------------------
__global__ __launch_bounds__(256) void conv2_mfma(
    const unsigned short* __restrict__ act1,
    const unsigned short* __restrict__ wrep,
    const float* __restrict__ bn_s, const float* __restrict__ bn_t,
    unsigned short* __restrict__ act2)
{
    constexpr int IC = 32, OC = 64, H = 112;
    __shared__ __align__(16) short lds[4*18*18*8];   // [chunk][y][x][8ic]

    const int tid = threadIdx.x;
    const int b = blockIdx.z;
    const int cx0 = blockIdx.x*16, cy0 = blockIdx.y*16;
    const unsigned short* ab = act1 + (size_t)b*H*H*IC;

    unsigned bad = 0;
    {
        int k = 0;
        for (int s = tid; s < 4*324; s += 256, ++k) {
            int ck = s / 324; int rem = s - ck*324;
            int y = rem / 18, xx = rem - y*18;
            int gy = cy0 - 1 + y, gx = cx0 - 1 + xx;
            if (!(((unsigned)gy < H) && ((unsigned)gx < H))) {
                bad |= 1u << k; gy = 0; gx = 0;
            }
            gload_lds16(ab + (size_t)(gy*H + gx)*IC + ck*8, &lds[s*8]);
        }
        if (bad) {
            asm volatile("s_waitcnt vmcnt(0)" ::: "memory");
            k = 0;
            for (int s = tid; s < 4*324; s += 256, ++k)
                if (bad & (1u << k)) {
                    uint4 z = {0u,0u,0u,0u};
                    *(uint4*)&lds[s*8] = z;
                }
        }
    }

    const int lane = tid & 63, wave = tid >> 6;
    const int n = lane & 15, quad = lane >> 4;
    const int oc0w = wave * 16;

    short8 afr[9];
#pragma unroll
    for (int t = 0; t < 9; ++t)
        afr[t] = *(const short8*)(wrep + (size_t)(t*OC + oc0w + n)*IC + quad*8);

    float4 sv = *(const float4*)(bn_s + oc0w + quad*4);
    float4 tv = *(const float4*)(bn_t + oc0w + quad*4);
    float sj[4] = {sv.x, sv.y, sv.z, sv.w};
    float tj[4] = {tv.x, tv.y, tv.z, tv.w};

    __syncthreads();

    floatx4 acc[3];
    float ev[4];

#pragma unroll
    for (int r = 0; r < 18; ++r) {
        const short* rp = &lds[((quad*18 + r)*18 + n)*8];
        short8 w0 = *(const short8*)(rp);
        short8 w1 = *(const short8*)(rp + 8);
        short8 w2 = *(const short8*)(rp + 16);

        if (r < 16) {
            floatx4 a = {0.f,0.f,0.f,0.f};
            a = MFMA(afr[0], w0, a);
            a = MFMA(afr[1], w1, a);
            a = MFMA(afr[2], w2, a);
            acc[r % 3] = a;
        }
        if (r >= 1 && r <= 16) {
            int y = r - 1;
            floatx4 a = acc[y % 3];
            a = MFMA(afr[3], w0, a);
            a = MFMA(afr[4], w1, a);
            a = MFMA(afr[5], w2, a);
            acc[y % 3] = a;
        }
        if (r >= 2) {
            int y = r - 2;
            floatx4 a = acc[y % 3];
            a = MFMA(afr[6], w0, a);
            a = MFMA(afr[7], w1, a);
            a = MFMA(afr[8], w2, a);

            float v[4];
#pragma unroll
            for (int j = 0; j < 4; ++j)
                v[j] = fmaxf(fmaf(a[j], sj[j], tj[j]), 0.f);

            if ((y & 1) == 0) {
#pragma unroll
                for (int j = 0; j < 4; ++j) ev[j] = v[j];
            } else {
                unsigned int pk[2];
#pragma unroll
                for (int j = 0; j < 4; ++j) {
                    float m = fmaxf(v[j], ev[j]);
                    m = fmaxf(m, __shfl_xor(m, 1));
                    unsigned short us = f2bf(m);
                    if (j & 1) pk[j >> 1] |= ((unsigned int)us) << 16;
                    else       pk[j >> 1]  = us;
                }
                if (!(n & 1)) {
                    int py = (cy0 >> 1) + (y >> 1), px = (cx0 >> 1) + (n >> 1);
                    unsigned short* dstp =
                        act2 + ((size_t)((b*56 + py)*56 + px))*OC + oc0w + quad*4;
                    *(uint2*)dstp = *(uint2*)pk;
                }
            }
        }
    }
}

// ---------------------------------------------------------------------------
// Kernel D: conv3 (64->128, 56x56) bf16 MFMA + bn + relu + spatial mean sum
// into feat (ws accumulator, zeroed by gen). R8 structure verbatim.
// ---------------------------------------------------------------------------
__global__ __launch_bounds__(256) void conv3_mfma(
    const unsigned short* __restrict__ act2,
    const unsigned short* __restrict__ wrep,
    const float* __restrict__ bn_s, const float* __restrict__ bn_t,
    float* __restrict__ feat)
{
    constexpr int IC = 64, OC = 128, H = 56;
    __shared__ __align__(16) short lds[8*16*18*8];   // [chunk][row16][col18][8ic]

    const int tid = threadIdx.x;
    const int b = blockIdx.z >> 1, half = blockIdx.z & 1;
    const int cx0 = blockIdx.x*16, cy0 = blockIdx.y*14;
    const unsigned short* ab = act2 + (size_t)b*H*H*IC;

    unsigned bad = 0;
    {
        int k = 0;
        for (int s = tid; s < 8*16*18; s += 256, ++k) {   // 2304 = 9 full rounds
            int ck = s / (16*18); int rem = s - ck*(16*18);
            int y = rem / 18, xx = rem - y*18;
            int gy = cy0 - 1 + y, gx = cx0 - 1 + xx;
            if (!(((unsigned)gy < H) && ((unsigned)gx < H))) {
                bad |= 1u << k; gy = 0; gx = 0;
            }
            gload_lds16(ab + (size_t)(gy*H + gx)*IC + ck*8, &lds[s*8]);
        }
        if (bad) {
            asm volatile("s_waitcnt vmcnt(0)" ::: "memory");
            k = 0;
            for (int s = tid; s < 8*16*18; s += 256, ++k)
                if (bad & (1u << k)) {
                    uint4 z = {0u,0u,0u,0u};
                    *(uint4*)&lds[s*8] = z;
                }
        }
    }

    const int lane = tid & 63, wave = tid >> 6;
    const int n = lane & 15, quad = lane >> 4;
    const int oc0w = half*64 + wave*16;

    short8 afr[18];   // [tap][kc]
#pragma unroll
    for (int t = 0; t < 9; ++t)
#pragma unroll
        for (int kc = 0; kc < 2; ++kc)
            afr[t*2 + kc] = *(const short8*)(wrep + (size_t)(t*OC + oc0w + n)*IC + kc*32 + quad*8);

    float4 sv = *(const float4*)(bn_s + oc0w + quad*4);
    float4 tv = *(const float4*)(bn_t + oc0w + quad*4);
    float sj[4] = {sv.x, sv.y, sv.z, sv.w};
    float tj[4] = {tv.x, tv.y, tv.z, tv.w};

    __syncthreads();

    float sum[4] = {0.f, 0.f, 0.f, 0.f};
    const bool vx = (cx0 + n) < H;
    floatx4 acc[3];

#pragma unroll
    for (int r = 0; r < 16; ++r) {
        const short* p0 = &lds[((quad*16     + r)*18 + n)*8];
        const short* p1 = &lds[(((4+quad)*16 + r)*18 + n)*8];
        short8 a0 = *(const short8*)(p0);
        short8 a1 = *(const short8*)(p0 + 8);
        short8 a2 = *(const short8*)(p0 + 16);
        short8 b0 = *(const short8*)(p1);
        short8 b1 = *(const short8*)(p1 + 8);
        short8 b2 = *(const short8*)(p1 + 16);

        if (r < 14) {                    // ky=0 for out y=r (init)
            floatx4 a = {0.f,0.f,0.f,0.f};
            a = MFMA(afr[0], a0, a);
            a = MFMA(afr[1], b0, a);
            a = MFMA(afr[2], a1, a);
            a = MFMA(afr[3], b1, a);
            a = MFMA(afr[4], a2, a);
            a = MFMA(afr[5], b2, a);
            acc[r % 3] = a;
        }
        if (r >= 1 && r <= 14) {         // ky=1 for out y=r-1
            int y = r - 1;
            floatx4 a = acc[y % 3];
            a = MFMA(afr[6],  a0, a);
            a = MFMA(afr[7],  b0, a);
            a = MFMA(afr[8],  a1, a);
            a = MFMA(afr[9],  b1, a);
            a = MFMA(afr[10], a2, a);
            a = MFMA(afr[11], b2, a);
            acc[y % 3] = a;
        }
        if (r >= 2) {                    // ky=2 for out y=r-2, finalize
            int y = r - 2;
            floatx4 a = acc[y % 3];
            a = MFMA(afr[12], a0, a);
            a = MFMA(afr[13], b0, a);
            a = MFMA(afr[14], a1, a);
            a = MFMA(afr[15], b1, a);
            a = MFMA(afr[16], a2, a);
            a = MFMA(afr[17], b2, a);
            if (vx) {
#pragma unroll
                for (int j = 0; j < 4; ++j)
                    sum[j] += fmaxf(fmaf(a[j], sj[j], tj[j]), 0.f);
            }
        }
    }
#pragma unroll
    for (int j = 0; j < 4; ++j) {
        sum[j] += __shfl_xor(sum[j], 1);
        sum[j] += __shfl_xor(sum[j], 2);
        sum[j] += __shfl_xor(sum[j], 4);
        sum[j] += __shfl_xor(sum[j], 8);
    }
    if (n == 0) {
#pragma unroll
        for (int j = 0; j < 4; ++j)
            atomicAdd(&feat[b*128 + oc0w + quad*4 + j], sum[j]);
    }
}

// ---------------------------------------------------------------------------
// Kernel E: FC head. 16 lanes per output, 200 blocks. Sole writer of d_out.
// ---------------------------------------------------------------------------
__global__ __launch_bounds__(256) void fc_kernel(
    const float* __restrict__ feat, const float* __restrict__ fc_w,
    const float* __restrict__ fc_b, float* __restrict__ out)
{
    int g = blockIdx.x * 16 + (threadIdx.x >> 4);   // output index b*100+n
    int l = threadIdx.x & 15;
    if (g >= BATCH*100) return;
    int b = g / 100, n = g - b*100;
    const float* f = feat + b*128 + l*8;
    const float* w = fc_w + (size_t)n*128 + l*8;
    float4 f0 = *(const float4*)(f);
    float4 f1 = *(const float4*)(f + 4);
    float4 w0 = *(const float4*)(w);
    float4 w1 = *(const float4*)(w + 4);
    float s = f0.x*w0.x + f0.y*w0.y + f0.z*w0.z + f0.w*w0.w
            + f1.x*w1.x + f1.y*w1.y + f1.z*w1.z + f1.w*w1.w;
    s += __shfl_xor(s, 1);
    s += __shfl_xor(s, 2);
    s += __shfl_xor(s, 4);
    s += __shfl_xor(s, 8);
    if (l == 0) out[g] = s * (1.f/3136.f) + fc_b[n];
}

extern "C" void kernel_launch(void* const* d_in, const int* in_sizes, int n_in,
                              void* d_out, int out_size, void* d_ws, size_t ws_size,
                              hipStream_t stream)
{
    const float* x       = (const float*)d_in[0];
    const float* w1      = (const float*)d_in[1];
    const float* b1      = (const float*)d_in[2];
    const float* w2      = (const float*)d_in[3];
    const float* b2      = (const float*)d_in[4];
    const float* w3      = (const float*)d_in[5];
    const float* b3      = (const float*)d_in[6];
    const float* wb      = (const float*)d_in[7];
    const float* bb      = (const float*)d_in[8];
    const float* conv2_w = (const float*)d_in[9];
    const float* conv2_b = (const float*)d_in[10];
    const float* conv3_w = (const float*)d_in[11];
    const float* conv3_b = (const float*)d_in[12];
    const float* bn1_g = (const float*)d_in[13];
    const float* bn1_b = (const float*)d_in[14];
    const float* bn1_m = (const float*)d_in[15];
    const float* bn1_v = (const float*)d_in[16];
    const float* bn2_g = (const float*)d_in[17];
    const float* bn2_b = (const float*)d_in[18];
    const float* bn2_m = (const float*)d_in[19];
    const float* bn2_v = (const float*)d_in[20];
    const float* bn3_g = (const float*)d_in[21];
    const float* bn3_b = (const float*)d_in[22];
    const float* bn3_m = (const float*)d_in[23];
    const float* bn3_v = (const float*)d_in[24];
    const float* fc_w  = (const float*)d_in[25];
    const float* fc_b  = (const float*)d_in[26];
    float* out = (float*)d_out;

    char* wsb = (char*)d_ws;
    float* ws    = (float*)d_ws;
    float* bn1_s = ws + 864;
    float* bn1_t = ws + 896;
    float* bn2_s = ws + 928;
    float* bn2_t = ws + 992;
    float* bn3_s = ws + 1056;
    float* bn3_t = ws + 1184;
    float* feat  = ws + 1312;                                  // bytes [5248,21632)
    unsigned short* swpre = (unsigned short*)(wsb + 24576);    // 2048 ush
    unsigned short* wrep2 = (unsigned short*)(wsb + 32768);    // 18432 ush
    unsigned short* wrep3 = (unsigned short*)(wsb + 69632);    // 73728 ush
    unsigned short* act1  = (unsigned short*)(wsb + 262144);   // 25.7MB
    unsigned short* act2  = (unsigned short*)(wsb + 262144 + 25690112); // 12.8MB

    gen_dynw<<<217, 256, 0, stream>>>(
        w1, b1, w2, b2, w3, b3,
        wb, bb, conv2_b, conv3_b,
        bn1_g, bn1_b, bn1_m, bn1_v, bn2_g, bn2_b, bn2_m, bn2_v,
        bn3_g, bn3_b, bn3_m, bn3_v,
        swpre,
        bn1_s, bn1_t, bn2_s, bn2_t, bn3_s, bn3_t, feat);

    conv1_pool<<<dim3(14, 14, BATCH), 256, 0, stream>>>(
        x, swpre, conv2_w, conv3_w, wrep2, wrep3, bn1_s, bn1_t, act1);

    conv2_mfma<<<dim3(7, 7, BATCH), 256, 0, stream>>>(
        act1, wrep2, bn2_s, bn2_t, act2);

    conv3_mfma<<<dim3(4, 4, BATCH*2), 256, 0, stream>>>(
        act2, wrep3, bn3_s, bn3_t, feat);

    fc_kernel<<<200, 256, 0, stream>>>(feat, fc_w, fc_b, out);
}